// Round 5
// baseline (685.969 us; speedup 1.0000x reference)
//
#include <hip/hip_runtime.h>

typedef __bf16 bf16x8 __attribute__((ext_vector_type(8)));
typedef __bf16 bf16x4 __attribute__((ext_vector_type(4)));
typedef float  f32x4  __attribute__((ext_vector_type(4)));

#define NH    16
#define SEQ   8192
#define EDIM  64
#define CHK   512
#define WCOLS 15872      // 512 + 15*1024
#define OUT0  8388608    // NH*SEQ*EDIM

#define MFMA(a, b, c) __builtin_amdgcn_mfma_f32_16x16x32_bf16((a), (b), (c), 0, 0, 0)

// ---------------------------------------------------------------------------
// Chunked attention, one block per (h, chunk, row-quadrant). 1024 blocks of
// 512 threads. Each block owns 128 q-rows; 8 waves x 16 rows. Computes S^T
// (MFMA operands swapped) so each lane owns one q-row with 4 consecutive
// key-cols per tile: f32x4 W stores, 2-shuffle softmax reductions, b64 LDS
// transpose writes.
//
// vs round-0 version: mt-split grid (4x blocks -> block pipelining overlaps
// one block's store drain with the next block's staging/compute), zero-fill
// folded in (32 f32x4 zero stores issued before __syncthreads so they drain
// under staging), and staging skips K/V rows >= 128*(mt+1) (fully masked).
// ---------------------------------------------------------------------------
__global__ __launch_bounds__(512, 2) void chunked_attn_kernel(
    const float* __restrict__ Qg, const float* __restrict__ Kg,
    const float* __restrict__ Vg, float* __restrict__ out)
{
    // K frags (A-layout rows s): idx = ((t*2+es)*4 + quad)*16 + l16 -> 64 KB
    __shared__ __align__(16) __bf16 lds_k[32768];
    // V^T frags (B-layout): idx = ((st*4+nt)*4 + quad)*16 + l16 -> 64 KB
    __shared__ __align__(16) __bf16 lds_v[32768];
    // per-wave P transpose buffer, double-buffered: 16 rows x stride 40
    __shared__ __align__(16) __bf16 lds_p[8][2][640];

    const int tid  = threadIdx.x;
    const int lane = tid & 63;
    const int wv   = __builtin_amdgcn_readfirstlane(tid >> 6);  // SGPR-uniform
    const int l16  = lane & 15;
    const int quad = lane >> 4;     // 0..3

    const int h  = blockIdx.x >> 6;
    const int n  = (blockIdx.x >> 2) & 15;
    const int mt = blockIdx.x & 3;         // row quadrant: rows [mt*128, mt*128+128)
    const int ns = (n == 0) ? 0 : n - 1;   // source chunk for K/V

    const size_t qbase = ((size_t)h * SEQ + (size_t)n  * CHK) * EDIM;
    const size_t kbase = ((size_t)h * SEQ + (size_t)ns * CHK) * EDIM;
    float* __restrict__ W = out + OUT0;
    const size_t wrow0   = (size_t)h * CHK;
    const int    colbase = (n == 0) ? 0 : (CHK + (n - 1) * 2 * CHK);

    const int m0   = mt * 128 + wv * 16;   // this wave's 16 q-rows
    const int tmax = mt * 8 + wv;          // last s-tile with any unmasked col (SGPR)
    const int qrow = m0 + l16;             // this lane's q-row

    // staging limit: K/V rows >= 128*(mt+1) are fully masked for this block
    const int clim = 1024 * (mt + 1);      // staging chunk-id bound (both loops)

    const float SC = 0.125f * 1.44269504088896340736f;  // scale * log2(e), folded into Q

    // ---- stage K as bf16 frags: lane(quad,l16) of slot (t,sub) holds
    // K[s=t*16+l16][e=sub*8..+7].
    #pragma unroll
    for (int it = 0; it < 8; ++it) {
        const int c = tid + it * 512;          // 4096 chunks of 8 elems
        if (c < clim) {
            const int s = c >> 3, sub = c & 7; // sub = es*4 + qd, e0 = sub*8
            const float* src = Kg + kbase + (size_t)s * EDIM + sub * 8;
            const float4 a = *(const float4*)src;
            const float4 b = *(const float4*)(src + 4);
            bf16x8 t;
            t[0] = (__bf16)a.x; t[1] = (__bf16)a.y; t[2] = (__bf16)a.z; t[3] = (__bf16)a.w;
            t[4] = (__bf16)b.x; t[5] = (__bf16)b.y; t[6] = (__bf16)b.z; t[7] = (__bf16)b.w;
            const int idx = ((s >> 4) * 8 + sub) * 16 + (s & 15);
            ((bf16x8*)lds_k)[idx] = t;
        }
    }

    // ---- stage V^T as bf16 B-frags (coalesced reads along e) ----
    #pragma unroll
    for (int it = 0; it < 8; ++it) {
        const int c = tid + it * 512;
        if (c < clim) {
            const int e = c & 63, sb = c >> 6;     // sb = st*4 + qd, s0 = sb*8
            bf16x8 t;
            #pragma unroll
            for (int j = 0; j < 8; ++j)
                t[j] = (__bf16)Vg[kbase + (size_t)(sb * 8 + j) * EDIM + e];
            const int idx = (((sb >> 2) * 4 + (e >> 4)) * 4 + (sb & 3)) * 16 + (e & 15);
            ((bf16x8*)lds_v)[idx] = t;
        }
    }

    // ---- Q fragments for this wave's rows (B-layout: col q=l16, k=e=quad*8+j) ----
    bf16x8 aq0, aq1;
    {
        const float* qp = Qg + qbase + (size_t)(m0 + l16) * EDIM + quad * 8;
        float4 a = *(const float4*)(qp);
        float4 b = *(const float4*)(qp + 4);
        aq0[0]=(__bf16)(a.x*SC); aq0[1]=(__bf16)(a.y*SC); aq0[2]=(__bf16)(a.z*SC); aq0[3]=(__bf16)(a.w*SC);
        aq0[4]=(__bf16)(b.x*SC); aq0[5]=(__bf16)(b.y*SC); aq0[6]=(__bf16)(b.z*SC); aq0[7]=(__bf16)(b.w*SC);
        a = *(const float4*)(qp + 32);
        b = *(const float4*)(qp + 36);
        aq1[0]=(__bf16)(a.x*SC); aq1[1]=(__bf16)(a.y*SC); aq1[2]=(__bf16)(a.z*SC); aq1[3]=(__bf16)(a.w*SC);
        aq1[4]=(__bf16)(b.x*SC); aq1[5]=(__bf16)(b.y*SC); aq1[6]=(__bf16)(b.z*SC); aq1[7]=(__bf16)(b.w*SC);
    }

    // ---- zero half-window (cols [n*1024, n*1024+512) == window cols 512..1023):
    // entirely masked for n>=1. Issue before the barrier so the drain overlaps
    // staging + compute of the whole block. ----
    if (n > 0) {
        float* const zp = W + (wrow0 + (size_t)qrow) * WCOLS + colbase + 512 + quad * 4;
        const f32x4 z = {0.f, 0.f, 0.f, 0.f};
        #pragma unroll
        for (int t = 0; t < 32; ++t)
            __builtin_nontemporal_store(z, (f32x4*)(zp + t * 16));
    }

    __syncthreads();

    const bf16x8* const kf = (const bf16x8*)lds_k;
    const bf16x8* const vf = (const bf16x8*)lds_v;

    // ---- S^T tiles: MFMA(K as A, Q as B) -> D[s][q]; lane(quad,l16):
    // q = l16, s = t*16 + quad*4 + r  (4 CONSECUTIVE key-cols per reg) ----
    f32x4 st[32];
    #pragma unroll
    for (int t = 0; t < 32; ++t) {
        if (t <= tmax) {                   // uniform SGPR branch: skip masked tiles
            const int kb = t * 128 + quad * 16 + l16;
            f32x4 acc = {0.f, 0.f, 0.f, 0.f};
            acc = MFMA(kf[kb],      aq0, acc);
            acc = MFMA(kf[kb + 64], aq1, acc);
            const int sb = t * 16 + quad * 4;
            #pragma unroll
            for (int r = 0; r < 4; ++r)
                acc[r] = (sb + r <= qrow) ? acc[r] : -3.0e38f;
            st[t] = acc;
        } else {
            st[t] = (f32x4){0.f, 0.f, 0.f, 0.f};   // stored as exact zeros
        }
    }

    // ---- row max: in-lane over up to 128 vals, then 2 shuffles across quads ----
    float mr = -3.0e38f;
    #pragma unroll
    for (int t = 0; t < 32; ++t) {
        if (t <= tmax) {
            #pragma unroll
            for (int r = 0; r < 4; ++r) mr = fmaxf(mr, st[t][r]);
        }
    }
    mr = fmaxf(mr, __shfl_xor(mr, 16));
    mr = fmaxf(mr, __shfl_xor(mr, 32));

    // ---- exp2 + row sum (masked -> exp2(-3e38 - mr) == 0 exactly) ----
    float lr = 0.f;
    #pragma unroll
    for (int t = 0; t < 32; ++t) {
        if (t <= tmax) {
            #pragma unroll
            for (int r = 0; r < 4; ++r) {
                const float e = __builtin_amdgcn_exp2f(st[t][r] - mr);
                st[t][r] = e;
                lr += e;
            }
        }
    }
    lr += __shfl_xor(lr, 16);
    lr += __shfl_xor(lr, 32);
    const float ri = __builtin_amdgcn_rcpf(lr);

    // ---- normalize in place (zero tiles stay zero) ----
    #pragma unroll
    for (int t = 0; t < 32; ++t) {
        if (t <= tmax) st[t] = st[t] * ri;
    }

    // ---- W store: one f32x4 per tile, full precision. Per instr: 16 rows
    // x 64 B contiguous (across quads). Fire-and-forget: no loads follow, so
    // no vmcnt wait ever blocks on the drain. ----
    {
        float* const wp = W + (wrow0 + (size_t)qrow) * WCOLS + colbase + quad * 4;
        #pragma unroll
        for (int t = 0; t < 32; ++t)
            __builtin_nontemporal_store(st[t], (f32x4*)(wp + t * 16));
    }

    // ---- PV: transpose P rows into A-frags via per-wave LDS (double-
    // buffered to break the WAR chain), skip all-zero s-blocks. ----
    f32x4 o0 = {0,0,0,0}, o1 = {0,0,0,0}, o2 = {0,0,0,0}, o3 = {0,0,0,0};
    #pragma unroll
    for (int pr = 0; pr < 16; ++pr) {
        if (2 * pr <= tmax) {              // uniform branch: P==0 beyond tmax
            __bf16* const pbuf = lds_p[wv][pr & 1];
            #pragma unroll
            for (int tt = 0; tt < 2; ++tt) {
                const int t = pr * 2 + tt;
                bf16x4 w;
                #pragma unroll
                for (int r = 0; r < 4; ++r) w[r] = (__bf16)st[t][r];
                // row q=l16, cols tt*16+quad*4..+3 (one ds_write_b64)
                *(bf16x4*)(pbuf + l16 * 40 + tt * 16 + quad * 4) = w;
            }
            // A-frag read: row l16, k = quad*8..+7 (in-wave DS ordering)
            const bf16x8 pa = *(const bf16x8*)(pbuf + l16 * 40 + quad * 8);
            const int vb = pr * 256 + quad * 16 + l16;
            o0 = MFMA(pa, vf[vb      ], o0);
            o1 = MFMA(pa, vf[vb +  64], o1);
            o2 = MFMA(pa, vf[vb + 128], o2);
            o3 = MFMA(pa, vf[vb + 192], o3);
        }
    }

    // ---- write O tile (C-layout rows = m0 + quad*4 + r, col l16) ----
    const int rq = m0 + quad * 4;
    const size_t ob = qbase + (size_t)rq * EDIM + l16;
    #pragma unroll
    for (int r = 0; r < 4; ++r) {
        __builtin_nontemporal_store(o0[r], out + ob + (size_t)r * EDIM     );
        __builtin_nontemporal_store(o1[r], out + ob + (size_t)r * EDIM + 16);
        __builtin_nontemporal_store(o2[r], out + ob + (size_t)r * EDIM + 32);
        __builtin_nontemporal_store(o3[r], out + ob + (size_t)r * EDIM + 48);
    }
}

extern "C" void kernel_launch(void* const* d_in, const int* in_sizes, int n_in,
                              void* d_out, int out_size, void* d_ws, size_t ws_size,
                              hipStream_t stream) {
    const float* Q = (const float*)d_in[0];
    const float* K = (const float*)d_in[1];
    const float* V = (const float*)d_in[2];
    float* out = (float*)d_out;
    chunked_attn_kernel<<<dim3(1024), dim3(512), 0, stream>>>(Q, K, V, out);
}

// Round 7
// 681.333 us; speedup vs baseline: 1.0068x; 1.0068x over previous
//
#include <hip/hip_runtime.h>

typedef __bf16 bf16x8 __attribute__((ext_vector_type(8)));
typedef __bf16 bf16x4 __attribute__((ext_vector_type(4)));
typedef float  f32x4  __attribute__((ext_vector_type(4)));

#define NH    16
#define SEQ   8192
#define EDIM  64
#define CHK   512
#define WCOLS 15872      // 512 + 15*1024
#define OUT0  8388608    // NH*SEQ*EDIM

#define MFMA(a, b, c) __builtin_amdgcn_mfma_f32_16x16x32_bf16((a), (b), (c), 0, 0, 0)

// ---------------------------------------------------------------------------
// Chunked attention, one block per (h, chunk, 64-row group). 2048 blocks of
// 256 threads (4 waves x 16 rows). Key window processed in 128-key tiles,
// double-buffered through a single 2x16KB LDS pool (K pass, then V pass
// reusing the same slots). S held fully in registers (st[32] f32x4 = full
// 512-key stripe per lane) -> one QK pass, global softmax, no recompute.
//
// Occupancy design (the point of this version): LDS 42KB + 4-wave blocks
// -> 2 blocks/CU co-resident (VGPR pool: 2 x ~200 <= 512/SIMD; LDS 84KB
// <= 160KB). 8 blocks/CU total -> staging, compute, and the 2.1MB/CU store
// drain overlap ACROSS blocks, which the previous 1-block/CU versions
// (R0: 650us, R5 mt-split without co-residency: 686us) could not do.
// Row-group is the SLOW blockIdx dim so the 8 blocks sharing one (h,n)
// K/V chunk land on the same XCD (round-robin heuristic) for L2 reuse.
// ---------------------------------------------------------------------------
__global__ __launch_bounds__(256, 2) void chunked_attn_kernel(
    const float* __restrict__ Qg, const float* __restrict__ Kg,
    const float* __restrict__ Vg, float* __restrict__ out)
{
    // 2 slots x 128 keys: K-frag layout idx=((s>>4)*8+sub)*16+(s&15), 16KB/slot.
    // Reused for V-frag tiles after the QK pass.
    __shared__ __align__(16) __bf16 lds_kv[2][8192];
    // per-wave P transpose buffer, double-buffered by pr parity
    __shared__ __align__(16) __bf16 lds_p[4][2][640];

    const int tid  = threadIdx.x;
    const int lane = tid & 63;
    const int wv   = __builtin_amdgcn_readfirstlane(tid >> 6);  // 0..3
    const int l16  = lane & 15;
    const int quad = lane >> 4;     // 0..3

    const int bid = blockIdx.x;
    const int g   = bid >> 8;       // 0..7 row group (slow dim -> XCD locality)
    const int hn  = bid & 255;
    const int h   = hn >> 4;
    const int n   = hn & 15;
    const int ns  = (n == 0) ? 0 : n - 1;   // source chunk for K/V

    const size_t qbase = ((size_t)h * SEQ + (size_t)n  * CHK) * EDIM;
    const size_t kbase = ((size_t)h * SEQ + (size_t)ns * CHK) * EDIM;
    float* __restrict__ W = out + OUT0;
    const size_t wrow0   = (size_t)h * CHK;
    const int    colbase = (n == 0) ? 0 : (CHK + (n - 1) * 2 * CHK);

    const int m0    = g * 64 + wv * 16;   // this wave's 16 q-rows (in-chunk)
    const int tmax  = g * 4 + wv;         // last 16-key s-tile with unmasked cols
    const int qrow  = m0 + l16;           // this lane's q-row
    const int ntile = (g + 2) >> 1;       // # of 128-key tiles needed (1..4)

    const float SC = 0.125f * 1.44269504088896340736f;  // scale * log2(e)

    // ---- zero half-window (cols colbase+512..+1023, always masked for n>=1).
    // Fire-and-forget before staging; drains under the whole block. ----
    if (n > 0) {
        float* const zp = W + (wrow0 + (size_t)qrow) * WCOLS + colbase + 512 + quad * 4;
        const f32x4 z = {0.f, 0.f, 0.f, 0.f};
        #pragma unroll
        for (int t = 0; t < 32; ++t)
            __builtin_nontemporal_store(z, (f32x4*)(zp + t * 16));
    }

    // ---- Q fragments (B-layout: col q=l16, k=e=quad*8+j), scale folded ----
    bf16x8 aq0, aq1;
    {
        const float* qp = Qg + qbase + (size_t)(m0 + l16) * EDIM + quad * 8;
        float4 a = *(const float4*)(qp);
        float4 b = *(const float4*)(qp + 4);
        aq0[0]=(__bf16)(a.x*SC); aq0[1]=(__bf16)(a.y*SC); aq0[2]=(__bf16)(a.z*SC); aq0[3]=(__bf16)(a.w*SC);
        aq0[4]=(__bf16)(b.x*SC); aq0[5]=(__bf16)(b.y*SC); aq0[6]=(__bf16)(b.z*SC); aq0[7]=(__bf16)(b.w*SC);
        a = *(const float4*)(qp + 32);
        b = *(const float4*)(qp + 36);
        aq1[0]=(__bf16)(a.x*SC); aq1[1]=(__bf16)(a.y*SC); aq1[2]=(__bf16)(a.z*SC); aq1[3]=(__bf16)(a.w*SC);
        aq1[4]=(__bf16)(b.x*SC); aq1[5]=(__bf16)(b.y*SC); aq1[6]=(__bf16)(b.z*SC); aq1[7]=(__bf16)(b.w*SC);
    }

    // ---- staging helpers (256 threads, 1024 16B-slots per 128-key tile) ----
    auto stageK = [&](int kt, int slot) {
        #pragma unroll
        for (int it = 0; it < 4; ++it) {
            const int c = tid + it * 256;
            const int s = c >> 3, sub = c & 7;     // s in 0..127, e0 = sub*8
            const float* src = Kg + kbase + (size_t)(kt * 128 + s) * EDIM + sub * 8;
            const float4 a = *(const float4*)src;
            const float4 b = *(const float4*)(src + 4);
            bf16x8 t;
            t[0] = (__bf16)a.x; t[1] = (__bf16)a.y; t[2] = (__bf16)a.z; t[3] = (__bf16)a.w;
            t[4] = (__bf16)b.x; t[5] = (__bf16)b.y; t[6] = (__bf16)b.z; t[7] = (__bf16)b.w;
            const int idx = ((s >> 4) * 8 + sub) * 16 + (s & 15);
            ((bf16x8*)lds_kv[slot])[idx] = t;
        }
    };
    auto stageV = [&](int kt, int slot) {
        #pragma unroll
        for (int it = 0; it < 4; ++it) {
            const int c = tid + it * 256;
            const int e = c & 63, sb = c >> 6;     // sb in 0..15, s0 = sb*8
            bf16x8 t;
            #pragma unroll
            for (int j = 0; j < 8; ++j)
                t[j] = (__bf16)Vg[kbase + (size_t)(kt * 128 + sb * 8 + j) * EDIM + e];
            const int idx = (((sb >> 2) * 4 + (e >> 4)) * 4 + (sb & 3)) * 16 + (e & 15);
            ((bf16x8*)lds_kv[slot])[idx] = t;
        }
    };

    // ---- S stripe registers: full 512-key window per lane, init 0 so
    // skipped tiles store exact zeros to W. ----
    f32x4 st[32];
    #pragma unroll
    for (int t = 0; t < 32; ++t) st[t] = (f32x4){0.f, 0.f, 0.f, 0.f};

    // ================= QK pass: 128-key tiles, double-buffered =============
    stageK(0, 0);
    #pragma unroll
    for (int kt = 0; kt < 4; ++kt) {
        if (kt < ntile) {                       // block-uniform guard
            __syncthreads();                    // tile kt visible; slot (kt+1)&1 free
            if (kt + 1 < ntile) stageK(kt + 1, (kt + 1) & 1);
            const bf16x8* const kf = (const bf16x8*)lds_kv[kt & 1];
            #pragma unroll
            for (int tt = 0; tt < 8; ++tt) {
                const int t = kt * 8 + tt;      // global 16-key s-tile
                if (t <= tmax) {                // wave-uniform triangular skip
                    const int kb = tt * 128 + quad * 16 + l16;
                    f32x4 acc = {0.f, 0.f, 0.f, 0.f};
                    acc = MFMA(kf[kb],      aq0, acc);
                    acc = MFMA(kf[kb + 64], aq1, acc);
                    if (t == tmax) {            // only the diagonal tile needs masking
                        const int sb = t * 16 + quad * 4;
                        #pragma unroll
                        for (int r = 0; r < 4; ++r)
                            acc[r] = (sb + r <= qrow) ? acc[r] : -3.0e38f;
                    }
                    st[t] = acc;
                }
            }
        }
    }

    // ================= softmax (S fully in registers) ======================
    float mr = -3.0e38f;
    #pragma unroll
    for (int t = 0; t < 32; ++t) {
        if (t <= tmax) {
            #pragma unroll
            for (int r = 0; r < 4; ++r) mr = fmaxf(mr, st[t][r]);
        }
    }
    mr = fmaxf(mr, __shfl_xor(mr, 16));
    mr = fmaxf(mr, __shfl_xor(mr, 32));

    float lr = 0.f;
    #pragma unroll
    for (int t = 0; t < 32; ++t) {
        if (t <= tmax) {
            #pragma unroll
            for (int r = 0; r < 4; ++r) {
                const float e = __builtin_amdgcn_exp2f(st[t][r] - mr);
                st[t][r] = e;                   // masked entries -> exact 0
                lr += e;
            }
        }
    }
    lr += __shfl_xor(lr, 16);
    lr += __shfl_xor(lr, 32);
    const float ri = __builtin_amdgcn_rcpf(lr);

    #pragma unroll
    for (int t = 0; t < 32; ++t) st[t] = st[t] * ri;   // zeros stay zero

    // ---- W store: 32 f32x4 nt stores per lane (64B x 16 rows per instr),
    // fire-and-forget; drains while the V pass runs. ----
    {
        float* const wp = W + (wrow0 + (size_t)qrow) * WCOLS + colbase + quad * 4;
        #pragma unroll
        for (int t = 0; t < 32; ++t)
            __builtin_nontemporal_store(st[t], (f32x4*)(wp + t * 16));
    }

    // ================= PV pass: V tiles through the same LDS pool ==========
    __syncthreads();          // all QK reads done before V overwrites slot 0
    stageV(0, 0);

    f32x4 o0 = {0,0,0,0}, o1 = {0,0,0,0}, o2 = {0,0,0,0}, o3 = {0,0,0,0};
    #pragma unroll
    for (int kt = 0; kt < 4; ++kt) {
        if (kt < ntile) {
            __syncthreads();
            if (kt + 1 < ntile) stageV(kt + 1, (kt + 1) & 1);
            const bf16x8* const vf = (const bf16x8*)lds_kv[kt & 1];
            #pragma unroll
            for (int pq = 0; pq < 4; ++pq) {    // 32-key sub-blocks of this tile
                const int pr = kt * 4 + pq;     // global 32-key block
                if (2 * pr <= tmax) {           // wave-uniform: P==0 beyond tmax
                    __bf16* const pbuf = lds_p[wv][pq & 1];
                    #pragma unroll
                    for (int tt = 0; tt < 2; ++tt) {
                        const int t = pr * 2 + tt;
                        bf16x4 w;
                        #pragma unroll
                        for (int r = 0; r < 4; ++r) w[r] = (__bf16)st[t][r];
                        // row q=l16, cols tt*16+quad*4..+3 (one ds_write_b64)
                        *(bf16x4*)(pbuf + l16 * 40 + tt * 16 + quad * 4) = w;
                    }
                    // A-frag read: row l16, k = quad*8..+7 (in-wave DS ordering)
                    const bf16x8 pa = *(const bf16x8*)(pbuf + l16 * 40 + quad * 8);
                    const int vb = pq * 256 + quad * 16 + l16;
                    o0 = MFMA(pa, vf[vb      ], o0);
                    o1 = MFMA(pa, vf[vb +  64], o1);
                    o2 = MFMA(pa, vf[vb + 128], o2);
                    o3 = MFMA(pa, vf[vb + 192], o3);
                }
            }
        }
    }

    // ---- write O tile (rows m0 + quad*4 + r, col l16) ----
    const int rq = m0 + quad * 4;
    const size_t ob = qbase + (size_t)rq * EDIM + l16;
    #pragma unroll
    for (int r = 0; r < 4; ++r) {
        __builtin_nontemporal_store(o0[r], out + ob + (size_t)r * EDIM     );
        __builtin_nontemporal_store(o1[r], out + ob + (size_t)r * EDIM + 16);
        __builtin_nontemporal_store(o2[r], out + ob + (size_t)r * EDIM + 32);
        __builtin_nontemporal_store(o3[r], out + ob + (size_t)r * EDIM + 48);
    }
}

extern "C" void kernel_launch(void* const* d_in, const int* in_sizes, int n_in,
                              void* d_out, int out_size, void* d_ws, size_t ws_size,
                              hipStream_t stream) {
    const float* Q = (const float*)d_in[0];
    const float* K = (const float*)d_in[1];
    const float* V = (const float*)d_in[2];
    float* out = (float*)d_out;
    chunked_attn_kernel<<<dim3(2048), dim3(256), 0, stream>>>(Q, K, V, out);
}

// Round 8
// 633.535 us; speedup vs baseline: 1.0828x; 1.0754x over previous
//
#include <hip/hip_runtime.h>

typedef __bf16 bf16x8 __attribute__((ext_vector_type(8)));
typedef __bf16 bf16x4 __attribute__((ext_vector_type(4)));
typedef float  f32x4  __attribute__((ext_vector_type(4)));

#define NH    16
#define SEQ   8192
#define EDIM  64
#define CHK   512
#define WCOLS 15872      // 512 + 15*1024
#define OUT0  8388608    // NH*SEQ*EDIM

#define MFMA(a, b, c) __builtin_amdgcn_mfma_f32_16x16x32_bf16((a), (b), (c), 0, 0, 0)

// ---------------------------------------------------------------------------
// Kernel A: zero the masked half-windows (cols [n*1024, n*1024+512) for each
// h, n>=1). LINEAR stores: 64 consecutive lanes x 16B = 1KB contiguous per
// wave-instr -> proven 6.3 TB/s fill rate (R0). 251.7 MB total.
// ---------------------------------------------------------------------------
__global__ __launch_bounds__(256) void zero_fill_kernel(float* __restrict__ W) {
    const int gid = blockIdx.x * 256 + threadIdx.x;   // 524288 threads
    #pragma unroll
    for (int it = 0; it < 30; ++it) {                 // 524288*30 = 15728640 x4-units
        const int i     = gid + it * 524288;
        const int j     = i & 127;                    // x4-unit within 512-f32 row
        const int rowid = i >> 7;
        const int r     = rowid & 511;
        const int w     = rowid >> 9;                 // 0..239 = h*15 + (n-1)
        const int h     = w / 15;
        const int n     = w - h * 15 + 1;             // 1..15
        float* p = W + (size_t)(h * 512 + r) * WCOLS + (size_t)n * 1024 + j * 4;
        f32x4 z = {0.f, 0.f, 0.f, 0.f};
        __builtin_nontemporal_store(z, (f32x4*)p);
    }
}

// ---------------------------------------------------------------------------
// Kernel B: chunked attention, one block per (h, chunk, 64-row group).
// 2048 blocks of 256 threads (4 waves x 16 rows). K/V in 128-key tiles,
// double-buffered through a 2x16KB LDS pool. S fully in registers.
//
// THIS ROUND'S CHANGE (store-granularity theory): W stores go through a
// per-wave [16][129] f32 LDS relay and are emitted as row-linear bursts --
// each store instr covers 2 rows x 512B CONTIGUOUS (lanes 0-31 row a,
// 32-63 row b) instead of 16 scattered 64B segments. Zero half-windows
// moved back to the linear zero_fill kernel (same theory).
// ---------------------------------------------------------------------------
__global__ __launch_bounds__(256, 2) void chunked_attn_kernel(
    const float* __restrict__ Qg, const float* __restrict__ Kg,
    const float* __restrict__ Vg, float* __restrict__ out)
{
    // 2 slots x 128 keys: frag layout idx=((s>>4)*8+sub)*16+(s&15), 16KB/slot
    __shared__ __align__(16) __bf16 lds_kv[2][8192];
    // per-wave P transpose buffer, double-buffered by pr parity
    __shared__ __align__(16) __bf16 lds_p[4][2][640];
    // per-wave W relay: 16 rows x (128+1) f32 (pad breaks bank conflicts)
    __shared__ __align__(16) float  lds_w[4][16 * 129];

    const int tid  = threadIdx.x;
    const int lane = tid & 63;
    const int wv   = __builtin_amdgcn_readfirstlane(tid >> 6);  // 0..3
    const int l16  = lane & 15;
    const int quad = lane >> 4;     // 0..3

    const int bid = blockIdx.x;
    const int g   = bid >> 8;       // 0..7 row group (slow dim -> XCD locality)
    const int hn  = bid & 255;
    const int h   = hn >> 4;
    const int n   = hn & 15;
    const int ns  = (n == 0) ? 0 : n - 1;   // source chunk for K/V

    const size_t qbase = ((size_t)h * SEQ + (size_t)n  * CHK) * EDIM;
    const size_t kbase = ((size_t)h * SEQ + (size_t)ns * CHK) * EDIM;
    float* __restrict__ W = out + OUT0;
    const size_t wrow0   = (size_t)h * CHK;
    const int    colbase = (n == 0) ? 0 : (CHK + (n - 1) * 2 * CHK);

    const int m0    = g * 64 + wv * 16;   // this wave's 16 q-rows (in-chunk)
    const int tmax  = g * 4 + wv;         // last 16-key s-tile with unmasked cols
    const int qrow  = m0 + l16;           // this lane's q-row
    const int ntile = (g + 2) >> 1;       // # of 128-key tiles needed (1..4)

    const float SC = 0.125f * 1.44269504088896340736f;  // scale * log2(e)

    // ---- Q fragments (B-layout: col q=l16, k=e=quad*8+j), scale folded ----
    bf16x8 aq0, aq1;
    {
        const float* qp = Qg + qbase + (size_t)(m0 + l16) * EDIM + quad * 8;
        float4 a = *(const float4*)(qp);
        float4 b = *(const float4*)(qp + 4);
        aq0[0]=(__bf16)(a.x*SC); aq0[1]=(__bf16)(a.y*SC); aq0[2]=(__bf16)(a.z*SC); aq0[3]=(__bf16)(a.w*SC);
        aq0[4]=(__bf16)(b.x*SC); aq0[5]=(__bf16)(b.y*SC); aq0[6]=(__bf16)(b.z*SC); aq0[7]=(__bf16)(b.w*SC);
        a = *(const float4*)(qp + 32);
        b = *(const float4*)(qp + 36);
        aq1[0]=(__bf16)(a.x*SC); aq1[1]=(__bf16)(a.y*SC); aq1[2]=(__bf16)(a.z*SC); aq1[3]=(__bf16)(a.w*SC);
        aq1[4]=(__bf16)(b.x*SC); aq1[5]=(__bf16)(b.y*SC); aq1[6]=(__bf16)(b.z*SC); aq1[7]=(__bf16)(b.w*SC);
    }

    // ---- staging helpers (256 threads, 1024 16B-slots per 128-key tile) ----
    auto stageK = [&](int kt, int slot) {
        #pragma unroll
        for (int it = 0; it < 4; ++it) {
            const int c = tid + it * 256;
            const int s = c >> 3, sub = c & 7;     // s in 0..127, e0 = sub*8
            const float* src = Kg + kbase + (size_t)(kt * 128 + s) * EDIM + sub * 8;
            const float4 a = *(const float4*)src;
            const float4 b = *(const float4*)(src + 4);
            bf16x8 t;
            t[0] = (__bf16)a.x; t[1] = (__bf16)a.y; t[2] = (__bf16)a.z; t[3] = (__bf16)a.w;
            t[4] = (__bf16)b.x; t[5] = (__bf16)b.y; t[6] = (__bf16)b.z; t[7] = (__bf16)b.w;
            const int idx = ((s >> 4) * 8 + sub) * 16 + (s & 15);
            ((bf16x8*)lds_kv[slot])[idx] = t;
        }
    };
    auto stageV = [&](int kt, int slot) {
        #pragma unroll
        for (int it = 0; it < 4; ++it) {
            const int c = tid + it * 256;
            const int e = c & 63, sb = c >> 6;     // sb in 0..15, s0 = sb*8
            bf16x8 t;
            #pragma unroll
            for (int j = 0; j < 8; ++j)
                t[j] = (__bf16)Vg[kbase + (size_t)(kt * 128 + sb * 8 + j) * EDIM + e];
            const int idx = (((sb >> 2) * 4 + (e >> 4)) * 4 + (sb & 3)) * 16 + (e & 15);
            ((bf16x8*)lds_kv[slot])[idx] = t;
        }
    };

    // ---- S stripe registers: full 512-key window per lane, init 0 so
    // skipped tiles store exact zeros to W. ----
    f32x4 st[32];
    #pragma unroll
    for (int t = 0; t < 32; ++t) st[t] = (f32x4){0.f, 0.f, 0.f, 0.f};

    // ================= QK pass: 128-key tiles, double-buffered =============
    stageK(0, 0);
    #pragma unroll
    for (int kt = 0; kt < 4; ++kt) {
        if (kt < ntile) {                       // block-uniform guard
            __syncthreads();                    // tile kt visible; slot (kt+1)&1 free
            if (kt + 1 < ntile) stageK(kt + 1, (kt + 1) & 1);
            const bf16x8* const kf = (const bf16x8*)lds_kv[kt & 1];
            #pragma unroll
            for (int tt = 0; tt < 8; ++tt) {
                const int t = kt * 8 + tt;      // global 16-key s-tile
                if (t <= tmax) {                // wave-uniform triangular skip
                    const int kb = tt * 128 + quad * 16 + l16;
                    f32x4 acc = {0.f, 0.f, 0.f, 0.f};
                    acc = MFMA(kf[kb],      aq0, acc);
                    acc = MFMA(kf[kb + 64], aq1, acc);
                    if (t == tmax) {            // only the diagonal tile needs masking
                        const int sb = t * 16 + quad * 4;
                        #pragma unroll
                        for (int r = 0; r < 4; ++r)
                            acc[r] = (sb + r <= qrow) ? acc[r] : -3.0e38f;
                    }
                    st[t] = acc;
                }
            }
        }
    }

    // ================= softmax (S fully in registers) ======================
    float mr = -3.0e38f;
    #pragma unroll
    for (int t = 0; t < 32; ++t) {
        if (t <= tmax) {
            #pragma unroll
            for (int r = 0; r < 4; ++r) mr = fmaxf(mr, st[t][r]);
        }
    }
    mr = fmaxf(mr, __shfl_xor(mr, 16));
    mr = fmaxf(mr, __shfl_xor(mr, 32));

    float lr = 0.f;
    #pragma unroll
    for (int t = 0; t < 32; ++t) {
        if (t <= tmax) {
            #pragma unroll
            for (int r = 0; r < 4; ++r) {
                const float e = __builtin_amdgcn_exp2f(st[t][r] - mr);
                st[t][r] = e;                   // masked entries -> exact 0
                lr += e;
            }
        }
    }
    lr += __shfl_xor(lr, 16);
    lr += __shfl_xor(lr, 32);
    const float ri = __builtin_amdgcn_rcpf(lr);

    #pragma unroll
    for (int t = 0; t < 32; ++t) st[t] = st[t] * ri;   // zeros stay zero

    // ---- all QK reads of lds_kv done; kick off V tile 0 so its HBM latency
    // hides under the W-store burst below ----
    __syncthreads();
    stageV(0, 0);

    // ================= W store: LDS relay -> row-linear bursts =============
    // Per 128-col chunk: stage [16][129] f32 per wave, then store 2 rows
    // (512B contiguous each) per instruction. In-wave DS ordering (same
    // pattern as lds_p) -- no barrier needed, lds_w is wave-private.
    {
        float* const lw = lds_w[wv];
        const int rr = lane >> 5;               // 0..1   burst row within pair
        const int cc = (lane & 31) * 4;         // 0..124 burst col (f32)
        #pragma unroll
        for (int ch = 0; ch < 4; ++ch) {
            #pragma unroll
            for (int tt = 0; tt < 8; ++tt)       // scatter regs into relay
                *(f32x4*)(lw + l16 * 129 + tt * 16 + quad * 4) = st[ch * 8 + tt];
            #pragma unroll
            for (int rp = 0; rp < 8; ++rp) {     // 8 instrs: 2 x 512B linear each
                const int row = rp * 2 + rr;
                const f32x4 v = *(const f32x4*)(lw + row * 129 + cc);
                __builtin_nontemporal_store(v,
                    (f32x4*)(W + (wrow0 + (size_t)(m0 + row)) * WCOLS
                               + colbase + ch * 128 + cc));
            }
        }
    }

    // ================= PV pass: V tiles through the same LDS pool ==========
    f32x4 o0 = {0,0,0,0}, o1 = {0,0,0,0}, o2 = {0,0,0,0}, o3 = {0,0,0,0};
    #pragma unroll
    for (int kt = 0; kt < 4; ++kt) {
        if (kt < ntile) {
            __syncthreads();
            if (kt + 1 < ntile) stageV(kt + 1, (kt + 1) & 1);
            const bf16x8* const vf = (const bf16x8*)lds_kv[kt & 1];
            #pragma unroll
            for (int pq = 0; pq < 4; ++pq) {    // 32-key sub-blocks of this tile
                const int pr = kt * 4 + pq;     // global 32-key block
                if (2 * pr <= tmax) {           // wave-uniform: P==0 beyond tmax
                    __bf16* const pbuf = lds_p[wv][pq & 1];
                    #pragma unroll
                    for (int tt = 0; tt < 2; ++tt) {
                        const int t = pr * 2 + tt;
                        bf16x4 w;
                        #pragma unroll
                        for (int r = 0; r < 4; ++r) w[r] = (__bf16)st[t][r];
                        // row q=l16, cols tt*16+quad*4..+3 (one ds_write_b64)
                        *(bf16x4*)(pbuf + l16 * 40 + tt * 16 + quad * 4) = w;
                    }
                    // A-frag read: row l16, k = quad*8..+7 (in-wave DS ordering)
                    const bf16x8 pa = *(const bf16x8*)(pbuf + l16 * 40 + quad * 8);
                    const int vb = pq * 256 + quad * 16 + l16;
                    o0 = MFMA(pa, vf[vb      ], o0);
                    o1 = MFMA(pa, vf[vb +  64], o1);
                    o2 = MFMA(pa, vf[vb + 128], o2);
                    o3 = MFMA(pa, vf[vb + 192], o3);
                }
            }
        }
    }

    // ---- write O tile (rows m0 + quad*4 + r, col l16) ----
    const int rq = m0 + quad * 4;
    const size_t ob = qbase + (size_t)rq * EDIM + l16;
    #pragma unroll
    for (int r = 0; r < 4; ++r) {
        __builtin_nontemporal_store(o0[r], out + ob + (size_t)r * EDIM     );
        __builtin_nontemporal_store(o1[r], out + ob + (size_t)r * EDIM + 16);
        __builtin_nontemporal_store(o2[r], out + ob + (size_t)r * EDIM + 32);
        __builtin_nontemporal_store(o3[r], out + ob + (size_t)r * EDIM + 48);
    }
}

extern "C" void kernel_launch(void* const* d_in, const int* in_sizes, int n_in,
                              void* d_out, int out_size, void* d_ws, size_t ws_size,
                              hipStream_t stream) {
    const float* Q = (const float*)d_in[0];
    const float* K = (const float*)d_in[1];
    const float* V = (const float*)d_in[2];
    float* out = (float*)d_out;
    zero_fill_kernel<<<dim3(2048), dim3(256), 0, stream>>>(out + OUT0);
    chunked_attn_kernel<<<dim3(2048), dim3(256), 0, stream>>>(Q, K, V, out);
}